// Round 7
// baseline (315.007 us; speedup 1.0000x reference)
//
#include <hip/hip_runtime.h>

// ---------------------------------------------------------------------------
// TemporalDifferentModuleMSDeformAttnVIZ — MI355X (gfx950)
// Round 7: R6 + (a) sampler occupancy 4->8 blocks/CU, (b) parallel detect_k.
// MFMA GEMMs (bf16, weights pre-transposed in ws) for value/proj/O;
// sampler: wave softmax, batched uint4 gathers, core overlaid into proj.
// Dtype-adaptive (flag: 0=bf16, 1=f32 inputs/outputs), f32 accumulate.
// Constants: D=256 NH=8 DH=32 L=4 NCP=4 TW=2 NTP=2 P=8
// Levels (T*H, W): TH={192,96,48,24} W={64,32,16,8} starts={0,12288,15360,16128}
// Lq=16320 = 255*64
// ---------------------------------------------------------------------------

typedef unsigned short bfraw;
typedef __attribute__((ext_vector_type(4))) float f32x4;
typedef __attribute__((ext_vector_type(8))) short bf16x8;

__device__ __forceinline__ float bf2f(bfraw u) {
  union { unsigned int i; float f; } v; v.i = ((unsigned int)u) << 16; return v.f;
}
__device__ __forceinline__ bfraw f2bf(float f) {
  union { float f; unsigned int i; } v; v.f = f;
  unsigned int x = v.i;
  return (bfraw)((x + 0x7FFFu + ((x >> 16) & 1u)) >> 16);  // RNE
}
__device__ __forceinline__ float lo16f(unsigned int w) {
  union { unsigned int i; float f; } v; v.i = w << 16; return v.f;
}
__device__ __forceinline__ float hi16f(unsigned int w) {
  union { unsigned int i; float f; } v; v.i = w & 0xFFFF0000u; return v.f;
}
__device__ __forceinline__ float loadx(const void* p, size_t i, int f32m) {
  if (f32m) return ((const float*)p)[i];
  else      return bf2f(((const bfraw*)p)[i]);
}

// Detect input dtype from `query` bytes (0 = bf16, 1 = f32). One wave: each
// lane scans 8 even-indexed bf16 slots; bf16 data lands in [1e-3,16) w.p.
// ~0.99, f32 mantissa-bit slots don't. Wave-reduce, lane 0 writes.
__global__ void detect_k(const void* q, int* flag) {
  const bfraw* b = (const bfraw*)q;
  const int t = threadIdx.x;   // 0..63
  int cnt = 0;
#pragma unroll
  for (int k = 0; k < 8; ++k) {
    float a = fabsf(bf2f(b[2 * (t * 8 + k)]));
    if (a > 0.0009765625f && a < 16.0f) ++cnt;
  }
#pragma unroll
  for (int m = 32; m >= 1; m >>= 1) cnt += __shfl_xor(cnt, m);
  if (t == 0) *flag = (cnt > 256) ? 0 : 1;
}

// Build transposed bf16 weights in ws:
// WT rows 0..255    = W_v^T   (WvT[n][k]   = W_v[k][n])
// WT rows 256..1023 = Wproj^T (cols: so 0-255 | tso 256-511 | aw 512-639 | taw 640-767)
// WT rows 1024..1279= W_o^T
// blocks 1280..1282: bcat[768] f32 = b_so|b_tso|b_aw|b_taw
__global__ __launch_bounds__(256) void transpose_k(
    const void* W_v, const void* W_so, const void* W_tso,
    const void* W_aw, const void* W_taw, const void* W_o,
    const void* b_so, const void* b_tso, const void* b_aw, const void* b_taw,
    bfraw* __restrict__ WT, float* __restrict__ bcat, const int* flagp)
{
  const int f32m = *flagp;
  const int b = blockIdx.x, t = threadIdx.x;
  if (b < 1280) {
    float s;
    if (b < 256)       s = loadx(W_v, (size_t)t * 256 + b, f32m);
    else if (b < 1024) {
      const int rp = b - 256;
      if (rp < 256)      s = loadx(W_so,  (size_t)t * 256 + rp, f32m);
      else if (rp < 512) s = loadx(W_tso, (size_t)t * 256 + (rp - 256), f32m);
      else if (rp < 640) s = loadx(W_aw,  (size_t)t * 128 + (rp - 512), f32m);
      else               s = loadx(W_taw, (size_t)t * 128 + (rp - 640), f32m);
    } else               s = loadx(W_o,  (size_t)t * 256 + (b - 1024), f32m);
    WT[(size_t)b * 256 + t] = f2bf(s);
  } else {
    const int i = (b - 1280) * 256 + t;
    if (i < 768) {
      float s;
      if (i < 256)      s = loadx(b_so,  i, f32m);
      else if (i < 512) s = loadx(b_tso, i - 256, f32m);
      else if (i < 640) s = loadx(b_aw,  i - 512, f32m);
      else              s = loadx(b_taw, i - 640, f32m);
      bcat[i] = s;
    }
  }
}

// MFMA GEMM: C[r0c+ (0..M)) x [bn..] = A[r0a..r0a+M) x K=256] @ WT^T + bias
// WT is bf16 [N][256] (row n = column n of W). Tile 64x64, BK=32, 4 waves.
// amode: 0 = A dtype per flag, 1 = A is internal bf16.
// cmode: 0 = C bf16 (internal ws), 1 = C dtype per flag.
// bmode: 0 = bias is f32 array, 1 = bias dtype per flag.
__global__ __launch_bounds__(256) void gemm_mfma(
    const void* __restrict__ A, const bfraw* __restrict__ WT,
    const void* __restrict__ bias, void* __restrict__ C,
    int lda, int ldc, int r0a, int r0c,
    int amode, int cmode, int bmode, const int* __restrict__ flagp)
{
  __shared__ bfraw As[64][40];   // [m][k], +8 pad
  __shared__ bfraw Bs[64][40];   // [n][k]
  const int f32m = *flagp;
  const int a_f32 = (amode == 0) ? f32m : 0;
  const int bm = blockIdx.x * 64;
  const int bn = blockIdx.y * 64;
  const int tid = threadIdx.x;
  const int srow = tid >> 2;           // 0..63
  const int skcol = (tid & 3) * 8;     // 0,8,16,24
  const int wave = tid >> 6;
  const int lane = tid & 63;
  const int quad = lane >> 4;
  const int l16 = lane & 15;

  f32x4 acc[4] = {};

  for (int k0 = 0; k0 < 256; k0 += 32) {
    uint4 pa;
    if (a_f32) {
      const float* Af = (const float*)A + (size_t)(r0a + bm + srow) * lda + (k0 + skcol);
      const float4 x = *(const float4*)Af;
      const float4 y = *(const float4*)(Af + 4);
      pa.x = (unsigned)f2bf(x.x) | ((unsigned)f2bf(x.y) << 16);
      pa.y = (unsigned)f2bf(x.z) | ((unsigned)f2bf(x.w) << 16);
      pa.z = (unsigned)f2bf(y.x) | ((unsigned)f2bf(y.y) << 16);
      pa.w = (unsigned)f2bf(y.z) | ((unsigned)f2bf(y.w) << 16);
    } else {
      pa = *(const uint4*)((const bfraw*)A + (size_t)(r0a + bm + srow) * lda + (k0 + skcol));
    }
    *(uint4*)&As[srow][skcol] = pa;
    *(uint4*)&Bs[srow][skcol] =
        *(const uint4*)(WT + (size_t)(bn + srow) * 256 + (k0 + skcol));
    __syncthreads();

    const bf16x8 af = *(const bf16x8*)&As[wave * 16 + l16][quad * 8];
#pragma unroll
    for (int j = 0; j < 4; ++j) {
      const bf16x8 bf = *(const bf16x8*)&Bs[j * 16 + l16][quad * 8];
      acc[j] = __builtin_amdgcn_mfma_f32_16x16x32_bf16(af, bf, acc[j], 0, 0, 0);
    }
    __syncthreads();
  }

  // epilogue: C/D layout col=lane&15, row=quad*4+reg
#pragma unroll
  for (int j = 0; j < 4; ++j) {
    const int col = bn + j * 16 + l16;
    const float bb = (bmode == 0) ? ((const float*)bias)[col] : loadx(bias, col, f32m);
#pragma unroll
    for (int r = 0; r < 4; ++r) {
      const int row = r0c + bm + wave * 16 + quad * 4 + r;
      const float v = acc[j][r] + bb;
      if (cmode == 0)      ((bfraw*)C)[(size_t)row * ldc + col] = f2bf(v);
      else if (f32m)       ((float*)C)[(size_t)row * ldc + col] = v;
      else                 ((bfraw*)C)[(size_t)row * ldc + col] = f2bf(v);
    }
  }
}

// One block per query, 256 threads. proj row (768 bf16):
// [0,256) cso | [256,512) tso | [512,640) caw | [640,768) taw.
// Writes core (bf16, 256) OVER proj row [0,256) (read-before-write in-block).
__global__ __launch_bounds__(256, 8) void sampler_k(
    bfraw* __restrict__ proj, const bfraw* __restrict__ value,
    const void* __restrict__ refp, const void* __restrict__ toff,
    int q0, const int* __restrict__ flagp)
{
  __shared__ int   s_idx[256][4];  // clamped pixel index (always valid)
  __shared__ float s_w[256][4];    // attn*bilinear, 0 if OOB

  const int f32m = *flagp;
  const int q = q0 + blockIdx.x;
  const int tid = threadIdx.x;
  const int h = tid >> 5;          // head
  const int sp = tid & 31;         // point-in-head
  const int l = sp >> 3;           // level
  const int p = sp & 7;            // 0..3 current, 4..7 temporal

  const int W_i[4]  = {64, 32, 16, 8};
  const int TH_i[4] = {192, 96, 48, 24};
  const int ST_i[4] = {0, 12288, 15360, 16128};
  const float Wf  = (float)W_i[l];
  const float THf = (float)TH_i[l];

  bfraw* prow = proj + (size_t)(q - q0) * 768;

  // ---- joint softmax over 32 logits per head (shfl within half-wave) ----
  const float logit = (p < 4) ? bf2f(prow[512 + h * 16 + l * 4 + p])
                              : bf2f(prow[640 + h * 16 + l * 4 + (p - 4)]);
  float mx = logit;
#pragma unroll
  for (int m = 16; m >= 1; m >>= 1) mx = fmaxf(mx, __shfl_xor(mx, m));
  const float e = __expf(logit - mx);
  float ssum = e;
#pragma unroll
  for (int m = 16; m >= 1; m >>= 1) ssum += __shfl_xor(ssum, m);
  const float attn = e / ssum;

  // ---- sampling location + bilinear corner descriptors ----
  const float rx = loadx(refp, (size_t)(q * 4 + l) * 2 + 0, f32m);
  const float ry = loadx(refp, (size_t)(q * 4 + l) * 2 + 1, f32m);
  float ox, oy;
  if (p < 4) {
    ox = bf2f(prow[h * 32 + l * 8 + p * 2 + 0]) / Wf;
    oy = bf2f(prow[h * 32 + l * 8 + p * 2 + 1]) / THf;
  } else {
    const int pj = p - 4, tw = pj >> 1, j = pj & 1;
    ox = loadx(toff, (size_t)(q * 4 + l) * 4 + tw * 2 + 0, f32m) +
         bf2f(prow[256 + h * 32 + l * 8 + tw * 4 + j * 2 + 0]) / Wf;
    oy = loadx(toff, (size_t)(q * 4 + l) * 4 + tw * 2 + 1, f32m) +
         bf2f(prow[256 + h * 32 + l * 8 + tw * 4 + j * 2 + 1]) / THf;
  }
  const float x = (rx + ox) * Wf - 0.5f;   // grid_sample align_corners=False
  const float y = (ry + oy) * THf - 0.5f;
  const float x0f = floorf(x), y0f = floorf(y);
  const float lx = x - x0f, ly = y - y0f;
  const int x0 = (int)x0f, y0 = (int)y0f;
  const int Wg = W_i[l], THg = TH_i[l], ST = ST_i[l];
  const float cwx[2] = {1.f - lx, lx};
  const float cwy[2] = {1.f - ly, ly};
#pragma unroll
  for (int c = 0; c < 4; ++c) {
    const int xi = x0 + (c & 1), yi = y0 + (c >> 1);
    const bool inb = (xi >= 0) & (xi < Wg) & (yi >= 0) & (yi < THg);
    const int xc = min(max(xi, 0), Wg - 1);
    const int yc = min(max(yi, 0), THg - 1);
    s_idx[tid][c] = ST + yc * Wg + xc;
    s_w[tid][c] = inb ? (attn * cwx[c & 1] * cwy[c >> 1]) : 0.f;
  }
  __syncthreads();

  // ---- gather: thread = (h, pt-group pg 0..7, ch-quad chq 0..3) ----
  {
    const int pg = sp >> 2;        // 4 points each
    const int chq = sp & 3;        // 8 channels each
    const bfraw* vb = value + h * 32 + chq * 8;
    int   idx[16];
    float ww[16];
#pragma unroll
    for (int pt = 0; pt < 4; ++pt) {
      const int ds = h * 32 + pg * 4 + pt;
#pragma unroll
      for (int c = 0; c < 4; ++c) { idx[pt * 4 + c] = s_idx[ds][c]; ww[pt * 4 + c] = s_w[ds][c]; }
    }
    uint4 vv[16];
#pragma unroll
    for (int i = 0; i < 16; ++i) vv[i] = *(const uint4*)(vb + (size_t)idx[i] * 256);
    float acc[8] = {};
#pragma unroll
    for (int i = 0; i < 16; ++i) {
      const float w = ww[i]; const uint4 v = vv[i];
      acc[0] += w * lo16f(v.x); acc[1] += w * hi16f(v.x);
      acc[2] += w * lo16f(v.y); acc[3] += w * hi16f(v.y);
      acc[4] += w * lo16f(v.z); acc[5] += w * hi16f(v.z);
      acc[6] += w * lo16f(v.w); acc[7] += w * hi16f(v.w);
    }
    // reduce over pg (sp bits 2..4): masks 4,8,16 within half-wave
#pragma unroll
    for (int m = 4; m <= 16; m <<= 1)
#pragma unroll
      for (int r = 0; r < 8; ++r)
        acc[r] += __shfl_xor(acc[r], m);
    if (pg == 0) {   // write core overlay: prow[0..256) := core (bf16)
      uint4 pk;
      pk.x = (unsigned)f2bf(acc[0]) | ((unsigned)f2bf(acc[1]) << 16);
      pk.y = (unsigned)f2bf(acc[2]) | ((unsigned)f2bf(acc[3]) << 16);
      pk.z = (unsigned)f2bf(acc[4]) | ((unsigned)f2bf(acc[5]) << 16);
      pk.w = (unsigned)f2bf(acc[6]) | ((unsigned)f2bf(acc[7]) << 16);
      *(uint4*)(prow + h * 32 + chq * 8) = pk;
    }
  }
}

extern "C" void kernel_launch(void* const* d_in, const int* in_sizes, int n_in,
                              void* d_out, int out_size, void* d_ws, size_t ws_size,
                              hipStream_t stream)
{
  const void* query  = d_in[0];
  const void* refp   = d_in[1];
  const void* toff   = d_in[2];
  const void* inflat = d_in[3];
  const void* W_so  = d_in[6];
  const void* b_so  = d_in[7];
  const void* W_tso = d_in[8];
  const void* b_tso = d_in[9];
  const void* W_aw  = d_in[10];
  const void* b_aw  = d_in[11];
  const void* W_taw = d_in[12];
  const void* b_taw = d_in[13];
  const void* W_v   = d_in[14];
  const void* b_v   = d_in[15];
  const void* W_o   = d_in[16];
  const void* b_o   = d_in[17];

  const int Lq = 16320;
  // ws layout: WT bf16 [1280][256] | bcat f32[768] | value bf16 [Lq][256] |
  //            proj bf16 [chunk][768] | ... | flag (last 4B)
  const size_t WT_B   = (size_t)1280 * 256 * 2;   // 655360
  const size_t BCAT_B = 768 * 4;                  // 3072
  const size_t VAL_B  = (size_t)Lq * 256 * 2;     // 8355840
  bfraw* WT    = (bfraw*)d_ws;
  float* bcat  = (float*)((char*)d_ws + WT_B);
  bfraw* value = (bfraw*)((char*)d_ws + WT_B + BCAT_B);
  bfraw* proj  = (bfraw*)((char*)d_ws + WT_B + BCAT_B + VAL_B);
  int*   flag  = (int*)((char*)d_ws + ((ws_size - 4) & ~(size_t)3));

  const size_t fixed = WT_B + BCAT_B + VAL_B + 64;
  size_t avail = (ws_size > fixed) ? (ws_size - fixed) : 0;
  long long chk = (long long)(avail / (768 * 2));
  chk &= ~63LL;
  if (chk > Lq) chk = Lq;
  if (chk < 64) chk = 64;
  const int chunk = (int)chk;

  const bfraw* WvT    = WT;                 // rows 0..255
  const bfraw* WprojT = WT + 256 * 256;     // rows 256..1023
  const bfraw* WoT    = WT + 1024 * 256;    // rows 1024..1279

  const dim3 blk(256);
  detect_k<<<dim3(1), dim3(64), 0, stream>>>(query, flag);
  transpose_k<<<dim3(1283), blk, 0, stream>>>(W_v, W_so, W_tso, W_aw, W_taw, W_o,
                                              b_so, b_tso, b_aw, b_taw, WT, bcat, flag);
  // value = inflat @ W_v + b_v  (bf16 out)
  gemm_mfma<<<dim3(Lq / 64, 4), blk, 0, stream>>>(
      inflat, WvT, b_v, value, 256, 256, 0, 0, /*amode*/0, /*cmode*/0, /*bmode*/1, flag);

  int q0 = 0;
  while (q0 < Lq) {
    int M = Lq - q0; if (M > chunk) M = chunk;   // multiples of 64
    gemm_mfma<<<dim3(M / 64, 12), blk, 0, stream>>>(
        query, WprojT, bcat, proj, 256, 768, q0, 0, /*amode*/0, /*cmode*/0, /*bmode*/0, flag);
    sampler_k<<<dim3(M), blk, 0, stream>>>(proj, value, refp, toff, q0, flag);
    gemm_mfma<<<dim3(M / 64, 4), blk, 0, stream>>>(
        proj, WoT, b_o, d_out, 768, 256, 0, q0, /*amode*/1, /*cmode*/1, /*bmode*/1, flag);
    q0 += M;
  }
}

// Round 8
// 259.864 us; speedup vs baseline: 1.2122x; 1.2122x over previous
//
#include <hip/hip_runtime.h>

// ---------------------------------------------------------------------------
// TemporalDifferentModuleMSDeformAttnVIZ — MI355X (gfx950)
// Round 8: R7 with the spill regression fixed: sampler gather in 2 batches of
// 8 uint4 loads, __launch_bounds__(256,6) (85-VGPR cap, 75% occupancy).
// R7's (256,8) forced VGPR=32 -> scratch spills -> WRITE_SIZE 8->318 MB.
// MFMA GEMMs (bf16, weights pre-transposed in ws) for value/proj/O;
// sampler: wave softmax, batched uint4 gathers, core overlaid into proj.
// Dtype-adaptive (flag: 0=bf16, 1=f32 inputs/outputs), f32 accumulate.
// Constants: D=256 NH=8 DH=32 L=4 NCP=4 TW=2 NTP=2 P=8
// Levels (T*H, W): TH={192,96,48,24} W={64,32,16,8} starts={0,12288,15360,16128}
// Lq=16320 = 255*64
// ---------------------------------------------------------------------------

typedef unsigned short bfraw;
typedef __attribute__((ext_vector_type(4))) float f32x4;
typedef __attribute__((ext_vector_type(8))) short bf16x8;

__device__ __forceinline__ float bf2f(bfraw u) {
  union { unsigned int i; float f; } v; v.i = ((unsigned int)u) << 16; return v.f;
}
__device__ __forceinline__ bfraw f2bf(float f) {
  union { float f; unsigned int i; } v; v.f = f;
  unsigned int x = v.i;
  return (bfraw)((x + 0x7FFFu + ((x >> 16) & 1u)) >> 16);  // RNE
}
__device__ __forceinline__ float lo16f(unsigned int w) {
  union { unsigned int i; float f; } v; v.i = w << 16; return v.f;
}
__device__ __forceinline__ float hi16f(unsigned int w) {
  union { unsigned int i; float f; } v; v.i = w & 0xFFFF0000u; return v.f;
}
__device__ __forceinline__ float loadx(const void* p, size_t i, int f32m) {
  if (f32m) return ((const float*)p)[i];
  else      return bf2f(((const bfraw*)p)[i]);
}

// Detect input dtype from `query` bytes (0 = bf16, 1 = f32). One wave: each
// lane scans 8 even-indexed bf16 slots; bf16 data lands in [1e-3,16) w.p.
// ~0.99, f32 mantissa-bit slots don't. Wave-reduce, lane 0 writes.
__global__ void detect_k(const void* q, int* flag) {
  const bfraw* b = (const bfraw*)q;
  const int t = threadIdx.x;   // 0..63
  int cnt = 0;
#pragma unroll
  for (int k = 0; k < 8; ++k) {
    float a = fabsf(bf2f(b[2 * (t * 8 + k)]));
    if (a > 0.0009765625f && a < 16.0f) ++cnt;
  }
#pragma unroll
  for (int m = 32; m >= 1; m >>= 1) cnt += __shfl_xor(cnt, m);
  if (t == 0) *flag = (cnt > 256) ? 0 : 1;
}

// Build transposed bf16 weights in ws:
// WT rows 0..255    = W_v^T   (WvT[n][k]   = W_v[k][n])
// WT rows 256..1023 = Wproj^T (cols: so 0-255 | tso 256-511 | aw 512-639 | taw 640-767)
// WT rows 1024..1279= W_o^T
// blocks 1280..1282: bcat[768] f32 = b_so|b_tso|b_aw|b_taw
__global__ __launch_bounds__(256) void transpose_k(
    const void* W_v, const void* W_so, const void* W_tso,
    const void* W_aw, const void* W_taw, const void* W_o,
    const void* b_so, const void* b_tso, const void* b_aw, const void* b_taw,
    bfraw* __restrict__ WT, float* __restrict__ bcat, const int* flagp)
{
  const int f32m = *flagp;
  const int b = blockIdx.x, t = threadIdx.x;
  if (b < 1280) {
    float s;
    if (b < 256)       s = loadx(W_v, (size_t)t * 256 + b, f32m);
    else if (b < 1024) {
      const int rp = b - 256;
      if (rp < 256)      s = loadx(W_so,  (size_t)t * 256 + rp, f32m);
      else if (rp < 512) s = loadx(W_tso, (size_t)t * 256 + (rp - 256), f32m);
      else if (rp < 640) s = loadx(W_aw,  (size_t)t * 128 + (rp - 512), f32m);
      else               s = loadx(W_taw, (size_t)t * 128 + (rp - 640), f32m);
    } else               s = loadx(W_o,  (size_t)t * 256 + (b - 1024), f32m);
    WT[(size_t)b * 256 + t] = f2bf(s);
  } else {
    const int i = (b - 1280) * 256 + t;
    if (i < 768) {
      float s;
      if (i < 256)      s = loadx(b_so,  i, f32m);
      else if (i < 512) s = loadx(b_tso, i - 256, f32m);
      else if (i < 640) s = loadx(b_aw,  i - 512, f32m);
      else              s = loadx(b_taw, i - 640, f32m);
      bcat[i] = s;
    }
  }
}

// MFMA GEMM: C[r0c+ (0..M)) x [bn..] = A[r0a..r0a+M) x K=256] @ WT^T + bias
// WT is bf16 [N][256] (row n = column n of W). Tile 64x64, BK=32, 4 waves.
// amode: 0 = A dtype per flag, 1 = A is internal bf16.
// cmode: 0 = C bf16 (internal ws), 1 = C dtype per flag.
// bmode: 0 = bias is f32 array, 1 = bias dtype per flag.
__global__ __launch_bounds__(256) void gemm_mfma(
    const void* __restrict__ A, const bfraw* __restrict__ WT,
    const void* __restrict__ bias, void* __restrict__ C,
    int lda, int ldc, int r0a, int r0c,
    int amode, int cmode, int bmode, const int* __restrict__ flagp)
{
  __shared__ bfraw As[64][40];   // [m][k], +8 pad
  __shared__ bfraw Bs[64][40];   // [n][k]
  const int f32m = *flagp;
  const int a_f32 = (amode == 0) ? f32m : 0;
  const int bm = blockIdx.x * 64;
  const int bn = blockIdx.y * 64;
  const int tid = threadIdx.x;
  const int srow = tid >> 2;           // 0..63
  const int skcol = (tid & 3) * 8;     // 0,8,16,24
  const int wave = tid >> 6;
  const int lane = tid & 63;
  const int quad = lane >> 4;
  const int l16 = lane & 15;

  f32x4 acc[4] = {};

  for (int k0 = 0; k0 < 256; k0 += 32) {
    uint4 pa;
    if (a_f32) {
      const float* Af = (const float*)A + (size_t)(r0a + bm + srow) * lda + (k0 + skcol);
      const float4 x = *(const float4*)Af;
      const float4 y = *(const float4*)(Af + 4);
      pa.x = (unsigned)f2bf(x.x) | ((unsigned)f2bf(x.y) << 16);
      pa.y = (unsigned)f2bf(x.z) | ((unsigned)f2bf(x.w) << 16);
      pa.z = (unsigned)f2bf(y.x) | ((unsigned)f2bf(y.y) << 16);
      pa.w = (unsigned)f2bf(y.z) | ((unsigned)f2bf(y.w) << 16);
    } else {
      pa = *(const uint4*)((const bfraw*)A + (size_t)(r0a + bm + srow) * lda + (k0 + skcol));
    }
    *(uint4*)&As[srow][skcol] = pa;
    *(uint4*)&Bs[srow][skcol] =
        *(const uint4*)(WT + (size_t)(bn + srow) * 256 + (k0 + skcol));
    __syncthreads();

    const bf16x8 af = *(const bf16x8*)&As[wave * 16 + l16][quad * 8];
#pragma unroll
    for (int j = 0; j < 4; ++j) {
      const bf16x8 bf = *(const bf16x8*)&Bs[j * 16 + l16][quad * 8];
      acc[j] = __builtin_amdgcn_mfma_f32_16x16x32_bf16(af, bf, acc[j], 0, 0, 0);
    }
    __syncthreads();
  }

  // epilogue: C/D layout col=lane&15, row=quad*4+reg
#pragma unroll
  for (int j = 0; j < 4; ++j) {
    const int col = bn + j * 16 + l16;
    const float bb = (bmode == 0) ? ((const float*)bias)[col] : loadx(bias, col, f32m);
#pragma unroll
    for (int r = 0; r < 4; ++r) {
      const int row = r0c + bm + wave * 16 + quad * 4 + r;
      const float v = acc[j][r] + bb;
      if (cmode == 0)      ((bfraw*)C)[(size_t)row * ldc + col] = f2bf(v);
      else if (f32m)       ((float*)C)[(size_t)row * ldc + col] = v;
      else                 ((bfraw*)C)[(size_t)row * ldc + col] = f2bf(v);
    }
  }
}

// One block per query, 256 threads. proj row (768 bf16):
// [0,256) cso | [256,512) tso | [512,640) caw | [640,768) taw.
// Writes core (bf16, 256) OVER proj row [0,256) (read-before-write in-block).
// launch_bounds (256,6): 85-VGPR cap — batch-of-8 gather fits WITHOUT spill
// (R7's (256,8) forced 32 VGPR -> scratch spills -> 318MB write traffic).
__global__ __launch_bounds__(256, 6) void sampler_k(
    bfraw* __restrict__ proj, const bfraw* __restrict__ value,
    const void* __restrict__ refp, const void* __restrict__ toff,
    int q0, const int* __restrict__ flagp)
{
  __shared__ int   s_idx[256][4];  // clamped pixel index (always valid)
  __shared__ float s_w[256][4];    // attn*bilinear, 0 if OOB

  const int f32m = *flagp;
  const int q = q0 + blockIdx.x;
  const int tid = threadIdx.x;
  const int h = tid >> 5;          // head
  const int sp = tid & 31;         // point-in-head
  const int l = sp >> 3;           // level
  const int p = sp & 7;            // 0..3 current, 4..7 temporal

  const int W_i[4]  = {64, 32, 16, 8};
  const int TH_i[4] = {192, 96, 48, 24};
  const int ST_i[4] = {0, 12288, 15360, 16128};
  const float Wf  = (float)W_i[l];
  const float THf = (float)TH_i[l];

  bfraw* prow = proj + (size_t)(q - q0) * 768;

  // ---- joint softmax over 32 logits per head (shfl within half-wave) ----
  const float logit = (p < 4) ? bf2f(prow[512 + h * 16 + l * 4 + p])
                              : bf2f(prow[640 + h * 16 + l * 4 + (p - 4)]);
  float mx = logit;
#pragma unroll
  for (int m = 16; m >= 1; m >>= 1) mx = fmaxf(mx, __shfl_xor(mx, m));
  const float e = __expf(logit - mx);
  float ssum = e;
#pragma unroll
  for (int m = 16; m >= 1; m >>= 1) ssum += __shfl_xor(ssum, m);
  const float attn = e / ssum;

  // ---- sampling location + bilinear corner descriptors ----
  const float rx = loadx(refp, (size_t)(q * 4 + l) * 2 + 0, f32m);
  const float ry = loadx(refp, (size_t)(q * 4 + l) * 2 + 1, f32m);
  float ox, oy;
  if (p < 4) {
    ox = bf2f(prow[h * 32 + l * 8 + p * 2 + 0]) / Wf;
    oy = bf2f(prow[h * 32 + l * 8 + p * 2 + 1]) / THf;
  } else {
    const int pj = p - 4, tw = pj >> 1, j = pj & 1;
    ox = loadx(toff, (size_t)(q * 4 + l) * 4 + tw * 2 + 0, f32m) +
         bf2f(prow[256 + h * 32 + l * 8 + tw * 4 + j * 2 + 0]) / Wf;
    oy = loadx(toff, (size_t)(q * 4 + l) * 4 + tw * 2 + 1, f32m) +
         bf2f(prow[256 + h * 32 + l * 8 + tw * 4 + j * 2 + 1]) / THf;
  }
  const float x = (rx + ox) * Wf - 0.5f;   // grid_sample align_corners=False
  const float y = (ry + oy) * THf - 0.5f;
  const float x0f = floorf(x), y0f = floorf(y);
  const float lx = x - x0f, ly = y - y0f;
  const int x0 = (int)x0f, y0 = (int)y0f;
  const int Wg = W_i[l], THg = TH_i[l], ST = ST_i[l];
  const float cwx[2] = {1.f - lx, lx};
  const float cwy[2] = {1.f - ly, ly};
#pragma unroll
  for (int c = 0; c < 4; ++c) {
    const int xi = x0 + (c & 1), yi = y0 + (c >> 1);
    const bool inb = (xi >= 0) & (xi < Wg) & (yi >= 0) & (yi < THg);
    const int xc = min(max(xi, 0), Wg - 1);
    const int yc = min(max(yi, 0), THg - 1);
    s_idx[tid][c] = ST + yc * Wg + xc;
    s_w[tid][c] = inb ? (attn * cwx[c & 1] * cwy[c >> 1]) : 0.f;
  }
  __syncthreads();

  // ---- gather: thread = (h, pt-group pg 0..7, ch-quad chq 0..3) ----
  // Two batches of 8 unconditional uint4 loads (no spill at 85-VGPR cap).
  {
    const int pg = sp >> 2;        // 4 points each
    const int chq = sp & 3;        // 8 channels each
    const bfraw* vb = value + h * 32 + chq * 8;
    float acc[8] = {};
#pragma unroll
    for (int half = 0; half < 2; ++half) {
      int   idx[8];
      float ww[8];
#pragma unroll
      for (int pt = 0; pt < 2; ++pt) {
        const int ds = h * 32 + pg * 4 + half * 2 + pt;
#pragma unroll
        for (int c = 0; c < 4; ++c) {
          idx[pt * 4 + c] = s_idx[ds][c];
          ww[pt * 4 + c]  = s_w[ds][c];
        }
      }
      uint4 vv[8];
#pragma unroll
      for (int i = 0; i < 8; ++i) vv[i] = *(const uint4*)(vb + (size_t)idx[i] * 256);
#pragma unroll
      for (int i = 0; i < 8; ++i) {
        const float w = ww[i]; const uint4 v = vv[i];
        acc[0] += w * lo16f(v.x); acc[1] += w * hi16f(v.x);
        acc[2] += w * lo16f(v.y); acc[3] += w * hi16f(v.y);
        acc[4] += w * lo16f(v.z); acc[5] += w * hi16f(v.z);
        acc[6] += w * lo16f(v.w); acc[7] += w * hi16f(v.w);
      }
    }
    // reduce over pg (sp bits 2..4): masks 4,8,16 within half-wave
#pragma unroll
    for (int m = 4; m <= 16; m <<= 1)
#pragma unroll
      for (int r = 0; r < 8; ++r)
        acc[r] += __shfl_xor(acc[r], m);
    if (pg == 0) {   // write core overlay: prow[0..256) := core (bf16)
      uint4 pk;
      pk.x = (unsigned)f2bf(acc[0]) | ((unsigned)f2bf(acc[1]) << 16);
      pk.y = (unsigned)f2bf(acc[2]) | ((unsigned)f2bf(acc[3]) << 16);
      pk.z = (unsigned)f2bf(acc[4]) | ((unsigned)f2bf(acc[5]) << 16);
      pk.w = (unsigned)f2bf(acc[6]) | ((unsigned)f2bf(acc[7]) << 16);
      *(uint4*)(prow + h * 32 + chq * 8) = pk;
    }
  }
}

extern "C" void kernel_launch(void* const* d_in, const int* in_sizes, int n_in,
                              void* d_out, int out_size, void* d_ws, size_t ws_size,
                              hipStream_t stream)
{
  const void* query  = d_in[0];
  const void* refp   = d_in[1];
  const void* toff   = d_in[2];
  const void* inflat = d_in[3];
  const void* W_so  = d_in[6];
  const void* b_so  = d_in[7];
  const void* W_tso = d_in[8];
  const void* b_tso = d_in[9];
  const void* W_aw  = d_in[10];
  const void* b_aw  = d_in[11];
  const void* W_taw = d_in[12];
  const void* b_taw = d_in[13];
  const void* W_v   = d_in[14];
  const void* b_v   = d_in[15];
  const void* W_o   = d_in[16];
  const void* b_o   = d_in[17];

  const int Lq = 16320;
  // ws layout: WT bf16 [1280][256] | bcat f32[768] | value bf16 [Lq][256] |
  //            proj bf16 [chunk][768] | ... | flag (last 4B)
  const size_t WT_B   = (size_t)1280 * 256 * 2;   // 655360
  const size_t BCAT_B = 768 * 4;                  // 3072
  const size_t VAL_B  = (size_t)Lq * 256 * 2;     // 8355840
  bfraw* WT    = (bfraw*)d_ws;
  float* bcat  = (float*)((char*)d_ws + WT_B);
  bfraw* value = (bfraw*)((char*)d_ws + WT_B + BCAT_B);
  bfraw* proj  = (bfraw*)((char*)d_ws + WT_B + BCAT_B + VAL_B);
  int*   flag  = (int*)((char*)d_ws + ((ws_size - 4) & ~(size_t)3));

  const size_t fixed = WT_B + BCAT_B + VAL_B + 64;
  size_t avail = (ws_size > fixed) ? (ws_size - fixed) : 0;
  long long chk = (long long)(avail / (768 * 2));
  chk &= ~63LL;
  if (chk > Lq) chk = Lq;
  if (chk < 64) chk = 64;
  const int chunk = (int)chk;

  const bfraw* WvT    = WT;                 // rows 0..255
  const bfraw* WprojT = WT + 256 * 256;     // rows 256..1023
  const bfraw* WoT    = WT + 1024 * 256;    // rows 1024..1279

  const dim3 blk(256);
  detect_k<<<dim3(1), dim3(64), 0, stream>>>(query, flag);
  transpose_k<<<dim3(1283), blk, 0, stream>>>(W_v, W_so, W_tso, W_aw, W_taw, W_o,
                                              b_so, b_tso, b_aw, b_taw, WT, bcat, flag);
  // value = inflat @ W_v + b_v  (bf16 out)
  gemm_mfma<<<dim3(Lq / 64, 4), blk, 0, stream>>>(
      inflat, WvT, b_v, value, 256, 256, 0, 0, /*amode*/0, /*cmode*/0, /*bmode*/1, flag);

  int q0 = 0;
  while (q0 < Lq) {
    int M = Lq - q0; if (M > chunk) M = chunk;   // multiples of 64
    gemm_mfma<<<dim3(M / 64, 12), blk, 0, stream>>>(
        query, WprojT, bcat, proj, 256, 768, q0, 0, /*amode*/0, /*cmode*/0, /*bmode*/0, flag);
    sampler_k<<<dim3(M), blk, 0, stream>>>(proj, value, refp, toff, q0, flag);
    gemm_mfma<<<dim3(M / 64, 4), blk, 0, stream>>>(
        proj, WoT, b_o, d_out, 768, 256, 0, q0, /*amode*/1, /*cmode*/1, /*bmode*/1, flag);
    q0 += M;
  }
}

// Round 9
// 254.639 us; speedup vs baseline: 1.2371x; 1.0205x over previous
//
#include <hip/hip_runtime.h>

// ---------------------------------------------------------------------------
// TemporalDifferentModuleMSDeformAttnVIZ — MI355X (gfx950)
// Round 9: GEMMs rewritten to 128x128 MFMA tiles (16 MFMA : 8 ds_read_b128
// per wave K-step; R8's 64x64 had 4:10 -> 67 TF total). Sampler reverted to
// R6's clean spill-free version (VGPR 44, (256,4)) — (256,6/8) caps spilled
// (WRITE_SIZE 8->90/318 MB).
// Dtype-adaptive (flag: 0=bf16, 1=f32 inputs/outputs), f32 accumulate.
// Constants: D=256 NH=8 DH=32 L=4 NCP=4 TW=2 NTP=2 P=8
// Levels (T*H, W): TH={192,96,48,24} W={64,32,16,8} starts={0,12288,15360,16128}
// Lq=16320 = 255*64 (= 127.5 x 128 -> M-tail handled by clamp/guard)
// ---------------------------------------------------------------------------

typedef unsigned short bfraw;
typedef __attribute__((ext_vector_type(4))) float f32x4;
typedef __attribute__((ext_vector_type(8))) short bf16x8;

__device__ __forceinline__ float bf2f(bfraw u) {
  union { unsigned int i; float f; } v; v.i = ((unsigned int)u) << 16; return v.f;
}
__device__ __forceinline__ bfraw f2bf(float f) {
  union { float f; unsigned int i; } v; v.f = f;
  unsigned int x = v.i;
  return (bfraw)((x + 0x7FFFu + ((x >> 16) & 1u)) >> 16);  // RNE
}
__device__ __forceinline__ float lo16f(unsigned int w) {
  union { unsigned int i; float f; } v; v.i = w << 16; return v.f;
}
__device__ __forceinline__ float hi16f(unsigned int w) {
  union { unsigned int i; float f; } v; v.i = w & 0xFFFF0000u; return v.f;
}
__device__ __forceinline__ float loadx(const void* p, size_t i, int f32m) {
  if (f32m) return ((const float*)p)[i];
  else      return bf2f(((const bfraw*)p)[i]);
}
__device__ __forceinline__ unsigned pk2(float a, float b) {
  return (unsigned)f2bf(a) | ((unsigned)f2bf(b) << 16);
}

// Detect input dtype from `query` bytes (0 = bf16, 1 = f32). One wave.
__global__ void detect_k(const void* q, int* flag) {
  const bfraw* b = (const bfraw*)q;
  const int t = threadIdx.x;   // 0..63
  int cnt = 0;
#pragma unroll
  for (int k = 0; k < 8; ++k) {
    float a = fabsf(bf2f(b[2 * (t * 8 + k)]));
    if (a > 0.0009765625f && a < 16.0f) ++cnt;
  }
#pragma unroll
  for (int m = 32; m >= 1; m >>= 1) cnt += __shfl_xor(cnt, m);
  if (t == 0) *flag = (cnt > 256) ? 0 : 1;
}

// Build transposed bf16 weights in ws:
// WT rows 0..255    = W_v^T ; rows 256..1023 = Wproj^T (so|tso|aw|taw cols)
// rows 1024..1279   = W_o^T ; bcat[768] f32 = b_so|b_tso|b_aw|b_taw
__global__ __launch_bounds__(256) void transpose_k(
    const void* W_v, const void* W_so, const void* W_tso,
    const void* W_aw, const void* W_taw, const void* W_o,
    const void* b_so, const void* b_tso, const void* b_aw, const void* b_taw,
    bfraw* __restrict__ WT, float* __restrict__ bcat, const int* flagp)
{
  const int f32m = *flagp;
  const int b = blockIdx.x, t = threadIdx.x;
  if (b < 1280) {
    float s;
    if (b < 256)       s = loadx(W_v, (size_t)t * 256 + b, f32m);
    else if (b < 1024) {
      const int rp = b - 256;
      if (rp < 256)      s = loadx(W_so,  (size_t)t * 256 + rp, f32m);
      else if (rp < 512) s = loadx(W_tso, (size_t)t * 256 + (rp - 256), f32m);
      else if (rp < 640) s = loadx(W_aw,  (size_t)t * 128 + (rp - 512), f32m);
      else               s = loadx(W_taw, (size_t)t * 128 + (rp - 640), f32m);
    } else               s = loadx(W_o,  (size_t)t * 256 + (b - 1024), f32m);
    WT[(size_t)b * 256 + t] = f2bf(s);
  } else {
    const int i = (b - 1280) * 256 + t;
    if (i < 768) {
      float s;
      if (i < 256)      s = loadx(b_so,  i, f32m);
      else if (i < 512) s = loadx(b_tso, i - 256, f32m);
      else if (i < 640) s = loadx(b_aw,  i - 512, f32m);
      else              s = loadx(b_taw, i - 640, f32m);
      bcat[i] = s;
    }
  }
}

// 128x128-tile MFMA GEMM, K=256 fixed. C rows [r0c, r0c+M) x cols [0,N) =
// A rows [r0a, r0a+M) @ WT^T + bias. WT bf16 [N][256]. N % 128 == 0.
// 256 thr / 4 waves; wave covers 64x64 via 4x4 16x16x32 MFMAs.
// amode: 0 = A dtype per flag, 1 = A internal bf16.
// cmode: 0 = C bf16 internal, 1 = C dtype per flag.
// bmode: 0 = bias f32 array, 1 = bias dtype per flag.
__global__ __launch_bounds__(256) void gemm128_k(
    const void* __restrict__ A, const bfraw* __restrict__ WT,
    const void* __restrict__ bias, void* __restrict__ C,
    int M, int lda, int ldc, int r0a, int r0c,
    int amode, int cmode, int bmode, const int* __restrict__ flagp)
{
  __shared__ bfraw As[128][40];   // [m][k], +8 pad: frag reads <=2-way conflict
  __shared__ bfraw Bs[128][40];   // [n][k]
  const int f32m = *flagp;
  const int a_f32 = (amode == 0) ? f32m : 0;
  const int bm = blockIdx.x * 128;
  const int bn = blockIdx.y * 128;
  const int tid = threadIdx.x;
  const int wave = tid >> 6, lane = tid & 63;
  const int quad = lane >> 4, l16 = lane & 15;
  const int mb = (wave >> 1) * 64, nb = (wave & 1) * 64;
  const int srow = tid >> 1;          // 0..127 staging row
  const int sk = (tid & 1) * 16;      // element offset 0 / 16

  int lr = bm + srow; if (lr >= M) lr = M - 1;       // clamp A tail reads
  const size_t aoff = (size_t)(r0a + lr) * lda;

  f32x4 acc[4][4] = {{{0.f}}};

  for (int k0 = 0; k0 < 256; k0 += 32) {
    uint4 pa0, pa1;
    if (a_f32) {
      const float* Af = (const float*)A + aoff + (k0 + sk);
      const float4 x0 = ((const float4*)Af)[0];
      const float4 x1 = ((const float4*)Af)[1];
      const float4 x2 = ((const float4*)Af)[2];
      const float4 x3 = ((const float4*)Af)[3];
      pa0.x = pk2(x0.x, x0.y); pa0.y = pk2(x0.z, x0.w);
      pa0.z = pk2(x1.x, x1.y); pa0.w = pk2(x1.z, x1.w);
      pa1.x = pk2(x2.x, x2.y); pa1.y = pk2(x2.z, x2.w);
      pa1.z = pk2(x3.x, x3.y); pa1.w = pk2(x3.z, x3.w);
    } else {
      const bfraw* Ab = (const bfraw*)A + aoff + (k0 + sk);
      pa0 = ((const uint4*)Ab)[0];
      pa1 = ((const uint4*)Ab)[1];
    }
    const bfraw* Bb = WT + (size_t)(bn + srow) * 256 + (k0 + sk);
    const uint4 pb0 = ((const uint4*)Bb)[0];
    const uint4 pb1 = ((const uint4*)Bb)[1];
    *(uint4*)&As[srow][sk]     = pa0;
    *(uint4*)&As[srow][sk + 8] = pa1;
    *(uint4*)&Bs[srow][sk]     = pb0;
    *(uint4*)&Bs[srow][sk + 8] = pb1;
    __syncthreads();

    bf16x8 af[4], bf[4];
#pragma unroll
    for (int i = 0; i < 4; ++i)
      af[i] = *(const bf16x8*)&As[mb + i * 16 + l16][quad * 8];
#pragma unroll
    for (int j = 0; j < 4; ++j)
      bf[j] = *(const bf16x8*)&Bs[nb + j * 16 + l16][quad * 8];
#pragma unroll
    for (int i = 0; i < 4; ++i)
#pragma unroll
      for (int j = 0; j < 4; ++j)
        acc[i][j] = __builtin_amdgcn_mfma_f32_16x16x32_bf16(af[i], bf[j], acc[i][j], 0, 0, 0);
    __syncthreads();
  }

  // epilogue: C/D layout col=lane&15, row=quad*4+reg
#pragma unroll
  for (int j = 0; j < 4; ++j) {
    const int col = bn + nb + j * 16 + l16;
    const float bb = (bmode == 0) ? ((const float*)bias)[col] : loadx(bias, col, f32m);
#pragma unroll
    for (int i = 0; i < 4; ++i) {
#pragma unroll
      for (int r = 0; r < 4; ++r) {
        const int lrow = bm + mb + i * 16 + quad * 4 + r;
        if (lrow < M) {
          const float v = acc[i][j][r] + bb;
          const size_t off = (size_t)(r0c + lrow) * ldc + col;
          if (cmode == 0)  ((bfraw*)C)[off] = f2bf(v);
          else if (f32m)   ((float*)C)[off] = v;
          else             ((bfraw*)C)[off] = f2bf(v);
        }
      }
    }
  }
}

// One block per query, 256 threads. proj row (768 bf16):
// [0,256) cso | [256,512) tso | [512,640) caw | [640,768) taw.
// Writes core (bf16, 256) OVER proj row [0,256) (read-before-write in-block).
// (256,4): VGPR cap 128 — compiler uses ~44, NO spill (R7/R8 lesson).
__global__ __launch_bounds__(256, 4) void sampler_k(
    bfraw* __restrict__ proj, const bfraw* __restrict__ value,
    const void* __restrict__ refp, const void* __restrict__ toff,
    int q0, const int* __restrict__ flagp)
{
  __shared__ int   s_idx[256][4];  // clamped pixel index (always valid)
  __shared__ float s_w[256][4];    // attn*bilinear, 0 if OOB

  const int f32m = *flagp;
  const int q = q0 + blockIdx.x;
  const int tid = threadIdx.x;
  const int h = tid >> 5;          // head
  const int sp = tid & 31;         // point-in-head
  const int l = sp >> 3;           // level
  const int p = sp & 7;            // 0..3 current, 4..7 temporal

  const int W_i[4]  = {64, 32, 16, 8};
  const int TH_i[4] = {192, 96, 48, 24};
  const int ST_i[4] = {0, 12288, 15360, 16128};
  const float Wf  = (float)W_i[l];
  const float THf = (float)TH_i[l];

  bfraw* prow = proj + (size_t)(q - q0) * 768;

  // ---- joint softmax over 32 logits per head (shfl within half-wave) ----
  const float logit = (p < 4) ? bf2f(prow[512 + h * 16 + l * 4 + p])
                              : bf2f(prow[640 + h * 16 + l * 4 + (p - 4)]);
  float mx = logit;
#pragma unroll
  for (int m = 16; m >= 1; m >>= 1) mx = fmaxf(mx, __shfl_xor(mx, m));
  const float e = __expf(logit - mx);
  float ssum = e;
#pragma unroll
  for (int m = 16; m >= 1; m >>= 1) ssum += __shfl_xor(ssum, m);
  const float attn = e / ssum;

  // ---- sampling location + bilinear corner descriptors ----
  const float rx = loadx(refp, (size_t)(q * 4 + l) * 2 + 0, f32m);
  const float ry = loadx(refp, (size_t)(q * 4 + l) * 2 + 1, f32m);
  float ox, oy;
  if (p < 4) {
    ox = bf2f(prow[h * 32 + l * 8 + p * 2 + 0]) / Wf;
    oy = bf2f(prow[h * 32 + l * 8 + p * 2 + 1]) / THf;
  } else {
    const int pj = p - 4, tw = pj >> 1, j = pj & 1;
    ox = loadx(toff, (size_t)(q * 4 + l) * 4 + tw * 2 + 0, f32m) +
         bf2f(prow[256 + h * 32 + l * 8 + tw * 4 + j * 2 + 0]) / Wf;
    oy = loadx(toff, (size_t)(q * 4 + l) * 4 + tw * 2 + 1, f32m) +
         bf2f(prow[256 + h * 32 + l * 8 + tw * 4 + j * 2 + 1]) / THf;
  }
  const float x = (rx + ox) * Wf - 0.5f;   // grid_sample align_corners=False
  const float y = (ry + oy) * THf - 0.5f;
  const float x0f = floorf(x), y0f = floorf(y);
  const float lx = x - x0f, ly = y - y0f;
  const int x0 = (int)x0f, y0 = (int)y0f;
  const int Wg = W_i[l], THg = TH_i[l], ST = ST_i[l];
  const float cwx[2] = {1.f - lx, lx};
  const float cwy[2] = {1.f - ly, ly};
#pragma unroll
  for (int c = 0; c < 4; ++c) {
    const int xi = x0 + (c & 1), yi = y0 + (c >> 1);
    const bool inb = (xi >= 0) & (xi < Wg) & (yi >= 0) & (yi < THg);
    const int xc = min(max(xi, 0), Wg - 1);
    const int yc = min(max(yi, 0), THg - 1);
    s_idx[tid][c] = ST + yc * Wg + xc;
    s_w[tid][c] = inb ? (attn * cwx[c & 1] * cwy[c >> 1]) : 0.f;
  }
  __syncthreads();

  // ---- gather: thread = (h, pt-group pg 0..7, ch-quad chq 0..3) ----
  {
    const int pg = sp >> 2;        // 4 points each
    const int chq = sp & 3;        // 8 channels each
    const bfraw* vb = value + h * 32 + chq * 8;
    int   idx[16];
    float ww[16];
#pragma unroll
    for (int pt = 0; pt < 4; ++pt) {
      const int ds = h * 32 + pg * 4 + pt;
#pragma unroll
      for (int c = 0; c < 4; ++c) { idx[pt * 4 + c] = s_idx[ds][c]; ww[pt * 4 + c] = s_w[ds][c]; }
    }
    uint4 vv[16];
#pragma unroll
    for (int i = 0; i < 16; ++i) vv[i] = *(const uint4*)(vb + (size_t)idx[i] * 256);
    float acc[8] = {};
#pragma unroll
    for (int i = 0; i < 16; ++i) {
      const float w = ww[i]; const uint4 v = vv[i];
      acc[0] += w * lo16f(v.x); acc[1] += w * hi16f(v.x);
      acc[2] += w * lo16f(v.y); acc[3] += w * hi16f(v.y);
      acc[4] += w * lo16f(v.z); acc[5] += w * hi16f(v.z);
      acc[6] += w * lo16f(v.w); acc[7] += w * hi16f(v.w);
    }
#pragma unroll
    for (int m = 4; m <= 16; m <<= 1)
#pragma unroll
      for (int r = 0; r < 8; ++r)
        acc[r] += __shfl_xor(acc[r], m);
    if (pg == 0) {   // write core overlay: prow[0..256) := core (bf16)
      uint4 pk;
      pk.x = pk2(acc[0], acc[1]);
      pk.y = pk2(acc[2], acc[3]);
      pk.z = pk2(acc[4], acc[5]);
      pk.w = pk2(acc[6], acc[7]);
      *(uint4*)(prow + h * 32 + chq * 8) = pk;
    }
  }
}

extern "C" void kernel_launch(void* const* d_in, const int* in_sizes, int n_in,
                              void* d_out, int out_size, void* d_ws, size_t ws_size,
                              hipStream_t stream)
{
  const void* query  = d_in[0];
  const void* refp   = d_in[1];
  const void* toff   = d_in[2];
  const void* inflat = d_in[3];
  const void* W_so  = d_in[6];
  const void* b_so  = d_in[7];
  const void* W_tso = d_in[8];
  const void* b_tso = d_in[9];
  const void* W_aw  = d_in[10];
  const void* b_aw  = d_in[11];
  const void* W_taw = d_in[12];
  const void* b_taw = d_in[13];
  const void* W_v   = d_in[14];
  const void* b_v   = d_in[15];
  const void* W_o   = d_in[16];
  const void* b_o   = d_in[17];

  const int Lq = 16320;
  // ws: WT bf16 [1280][256] | bcat f32[768] | value bf16 [Lq][256] |
  //     proj bf16 [chunk][768] | ... | flag (last 4B)
  const size_t WT_B   = (size_t)1280 * 256 * 2;
  const size_t BCAT_B = 768 * 4;
  const size_t VAL_B  = (size_t)Lq * 256 * 2;
  bfraw* WT    = (bfraw*)d_ws;
  float* bcat  = (float*)((char*)d_ws + WT_B);
  bfraw* value = (bfraw*)((char*)d_ws + WT_B + BCAT_B);
  bfraw* proj  = (bfraw*)((char*)d_ws + WT_B + BCAT_B + VAL_B);
  int*   flag  = (int*)((char*)d_ws + ((ws_size - 4) & ~(size_t)3));

  const size_t fixed = WT_B + BCAT_B + VAL_B + 64;
  size_t avail = (ws_size > fixed) ? (ws_size - fixed) : 0;
  long long chk = (long long)(avail / (768 * 2));
  chk &= ~63LL;
  if (chk > Lq) chk = Lq;
  if (chk < 64) chk = 64;
  const int chunk = (int)chk;

  const bfraw* WvT    = WT;                 // rows 0..255
  const bfraw* WprojT = WT + 256 * 256;     // rows 256..1023
  const bfraw* WoT    = WT + 1024 * 256;    // rows 1024..1279

  const dim3 blk(256);
  detect_k<<<dim3(1), dim3(64), 0, stream>>>(query, flag);
  transpose_k<<<dim3(1283), blk, 0, stream>>>(W_v, W_so, W_tso, W_aw, W_taw, W_o,
                                              b_so, b_tso, b_aw, b_taw, WT, bcat, flag);
  // value = inflat @ W_v + b_v  (bf16 out)
  gemm128_k<<<dim3((Lq + 127) / 128, 2), blk, 0, stream>>>(
      inflat, WvT, b_v, value, Lq, 256, 256, 0, 0, /*amode*/0, /*cmode*/0, /*bmode*/1, flag);

  int q0 = 0;
  while (q0 < Lq) {
    int M = Lq - q0; if (M > chunk) M = chunk;   // multiple of 64
    gemm128_k<<<dim3((M + 127) / 128, 6), blk, 0, stream>>>(
        query, WprojT, bcat, proj, M, 256, 768, q0, 0, /*amode*/0, /*cmode*/0, /*bmode*/0, flag);
    sampler_k<<<dim3(M), blk, 0, stream>>>(proj, value, refp, toff, q0, flag);
    gemm128_k<<<dim3((M + 127) / 128, 2), blk, 0, stream>>>(
        proj, WoT, b_o, d_out, M, 768, 256, 0, q0, /*amode*/1, /*cmode*/1, /*bmode*/1, flag);
    q0 += M;
  }
}

// Round 10
// 247.573 us; speedup vs baseline: 1.2724x; 1.0285x over previous
//
#include <hip/hip_runtime.h>

// ---------------------------------------------------------------------------
// TemporalDifferentModuleMSDeformAttnVIZ — MI355X (gfx950)
// Round 10: (1) sampler restructured head-major — block = 8 queries x 1 head,
// grid (2040, 8); x-major dispatch sweeps heads so live value working set is
// ~1 MB (per-head 64B-line slice) < 4MiB per-XCD L2. R9 block=query touched
// all 8 heads -> 8.4MB set -> 142MB FETCH = the whole 87us.
// (2) dispatches 7 -> 4: detect_k removed (per-kernel uniform dtype vote),
// value+proj GEMMs fused into one dispatch.
// Constants: D=256 NH=8 DH=32 L=4 NCP=4 TW=2 NTP=2 P=8
// Levels (T*H, W): TH={192,96,48,24} W={64,32,16,8} starts={0,12288,15360,16128}
// Lq=16320
// ---------------------------------------------------------------------------

typedef unsigned short bfraw;
typedef __attribute__((ext_vector_type(4))) float f32x4;
typedef __attribute__((ext_vector_type(8))) short bf16x8;

__device__ __forceinline__ float bf2f(bfraw u) {
  union { unsigned int i; float f; } v; v.i = ((unsigned int)u) << 16; return v.f;
}
__device__ __forceinline__ bfraw f2bf(float f) {
  union { float f; unsigned int i; } v; v.f = f;
  unsigned int x = v.i;
  return (bfraw)((x + 0x7FFFu + ((x >> 16) & 1u)) >> 16);  // RNE
}
__device__ __forceinline__ float lo16f(unsigned int w) {
  union { unsigned int i; float f; } v; v.i = w << 16; return v.f;
}
__device__ __forceinline__ float hi16f(unsigned int w) {
  union { unsigned int i; float f; } v; v.i = w & 0xFFFF0000u; return v.f;
}
__device__ __forceinline__ float loadx(const void* p, size_t i, int f32m) {
  if (f32m) return ((const float*)p)[i];
  else      return bf2f(((const bfraw*)p)[i]);
}
__device__ __forceinline__ unsigned pk2(float a, float b) {
  return (unsigned)f2bf(a) | ((unsigned)f2bf(b) << 16);
}

// Uniform dtype vote from the first 64 B of `query` (kernel-arg pointer ->
// scalar loads). bf16 data: low half of each dword is a ~N(0,1) sample,
// |x| in [1e-3,16) w.p. ~0.9985 -> cnt~16. f32 data: low halves are mantissa
// bits -> ~5% in range -> cnt~1. P(wrong vote) < 1e-6. Returns 1 = f32.
__device__ __forceinline__ int vote_f32(const void* q) {
  const unsigned* p = (const unsigned*)q;
  int cnt = 0;
#pragma unroll
  for (int i = 0; i < 16; ++i) {
    const float a = fabsf(lo16f(p[i]));
    cnt += (a > 0.0009765625f && a < 16.0f) ? 1 : 0;
  }
  return (cnt >= 8) ? 0 : 1;
}

// Build transposed bf16 weights in ws:
// WT rows 0..255 = W_v^T ; 256..1023 = Wproj^T (so|tso|aw|taw col order);
// 1024..1279 = W_o^T. Blocks 1280..1282: bcat[768] f32 = b_so|b_tso|b_aw|b_taw.
__global__ __launch_bounds__(256) void transpose_k(
    const void* W_v, const void* W_so, const void* W_tso,
    const void* W_aw, const void* W_taw, const void* W_o,
    const void* b_so, const void* b_tso, const void* b_aw, const void* b_taw,
    bfraw* __restrict__ WT, float* __restrict__ bcat, const void* query)
{
  const int f32m = vote_f32(query);
  const int b = blockIdx.x, t = threadIdx.x;
  if (b < 1280) {
    float s;
    if (b < 256)       s = loadx(W_v, (size_t)t * 256 + b, f32m);
    else if (b < 1024) {
      const int rp = b - 256;
      if (rp < 256)      s = loadx(W_so,  (size_t)t * 256 + rp, f32m);
      else if (rp < 512) s = loadx(W_tso, (size_t)t * 256 + (rp - 256), f32m);
      else if (rp < 640) s = loadx(W_aw,  (size_t)t * 128 + (rp - 512), f32m);
      else               s = loadx(W_taw, (size_t)t * 128 + (rp - 640), f32m);
    } else               s = loadx(W_o,  (size_t)t * 256 + (b - 1024), f32m);
    WT[(size_t)b * 256 + t] = f2bf(s);
  } else {
    const int i = (b - 1280) * 256 + t;
    if (i < 768) {
      float s;
      if (i < 256)      s = loadx(b_so,  i, f32m);
      else if (i < 512) s = loadx(b_tso, i - 256, f32m);
      else if (i < 640) s = loadx(b_aw,  i - 512, f32m);
      else              s = loadx(b_taw, i - 640, f32m);
      bcat[i] = s;
    }
  }
}

// Fused value + proj GEMM. 128x128 tiles, K=256, M=16320 (tail-guarded).
// blockIdx.y 0..1: value = inflat @ WvT^T + b_v   -> value bf16 ldc 256
// blockIdx.y 2..7: proj  = query  @ WprojT^T + bcat -> proj bf16 ldc 768
__global__ __launch_bounds__(256) void gemmVP_k(
    const void* __restrict__ inflat, const void* __restrict__ query,
    const bfraw* __restrict__ WT, const void* __restrict__ b_v,
    const float* __restrict__ bcat,
    bfraw* __restrict__ value, bfraw* __restrict__ proj, int M)
{
  __shared__ bfraw As[128][40];   // [m][k], +8 pad
  __shared__ bfraw Bs[128][40];   // [n][k]
  const int f32m = vote_f32(query);
  const int y = blockIdx.y;
  const void* A; bfraw* C; int ldc, wtb, colb, bmode;
  if (y < 2) { A = inflat; C = value; ldc = 256; wtb = y * 128;           colb = y * 128;       bmode = 1; }
  else       { A = query;  C = proj;  ldc = 768; wtb = 256 + (y - 2) * 128; colb = (y - 2) * 128; bmode = 0; }

  const int bm = blockIdx.x * 128;
  const int tid = threadIdx.x;
  const int wave = tid >> 6, lane = tid & 63;
  const int quad = lane >> 4, l16 = lane & 15;
  const int mb = (wave >> 1) * 64, nb = (wave & 1) * 64;
  const int srow = tid >> 1;
  const int sk = (tid & 1) * 16;

  int lr = bm + srow; if (lr >= M) lr = M - 1;
  const size_t aoff = (size_t)lr * 256;

  f32x4 acc[4][4] = {{{0.f}}};

  for (int k0 = 0; k0 < 256; k0 += 32) {
    uint4 pa0, pa1;
    if (f32m) {
      const float* Af = (const float*)A + aoff + (k0 + sk);
      const float4 x0 = ((const float4*)Af)[0];
      const float4 x1 = ((const float4*)Af)[1];
      const float4 x2 = ((const float4*)Af)[2];
      const float4 x3 = ((const float4*)Af)[3];
      pa0.x = pk2(x0.x, x0.y); pa0.y = pk2(x0.z, x0.w);
      pa0.z = pk2(x1.x, x1.y); pa0.w = pk2(x1.z, x1.w);
      pa1.x = pk2(x2.x, x2.y); pa1.y = pk2(x2.z, x2.w);
      pa1.z = pk2(x3.x, x3.y); pa1.w = pk2(x3.z, x3.w);
    } else {
      const bfraw* Ab = (const bfraw*)A + aoff + (k0 + sk);
      pa0 = ((const uint4*)Ab)[0];
      pa1 = ((const uint4*)Ab)[1];
    }
    const bfraw* Bb = WT + (size_t)(wtb + srow) * 256 + (k0 + sk);
    const uint4 pb0 = ((const uint4*)Bb)[0];
    const uint4 pb1 = ((const uint4*)Bb)[1];
    *(uint4*)&As[srow][sk]     = pa0;
    *(uint4*)&As[srow][sk + 8] = pa1;
    *(uint4*)&Bs[srow][sk]     = pb0;
    *(uint4*)&Bs[srow][sk + 8] = pb1;
    __syncthreads();

    bf16x8 af[4], bf[4];
#pragma unroll
    for (int i = 0; i < 4; ++i)
      af[i] = *(const bf16x8*)&As[mb + i * 16 + l16][quad * 8];
#pragma unroll
    for (int j = 0; j < 4; ++j)
      bf[j] = *(const bf16x8*)&Bs[nb + j * 16 + l16][quad * 8];
#pragma unroll
    for (int i = 0; i < 4; ++i)
#pragma unroll
      for (int j = 0; j < 4; ++j)
        acc[i][j] = __builtin_amdgcn_mfma_f32_16x16x32_bf16(af[i], bf[j], acc[i][j], 0, 0, 0);
    __syncthreads();
  }

#pragma unroll
  for (int j = 0; j < 4; ++j) {
    const int col = colb + nb + j * 16 + l16;
    const float bb = bmode ? loadx(b_v, col, f32m) : bcat[col];
#pragma unroll
    for (int i = 0; i < 4; ++i) {
#pragma unroll
      for (int r = 0; r < 4; ++r) {
        const int lrow = bm + mb + i * 16 + quad * 4 + r;
        if (lrow < M) C[(size_t)lrow * ldc + col] = f2bf(acc[i][j][r] + bb);
      }
    }
  }
}

// O-projection GEMM: out[0..M) = core @ W_o + b_o; core = proj rows cols[0,256)
// (bf16, stride 768, written by sampler overlay). C dtype per vote.
__global__ __launch_bounds__(256) void gemmO_k(
    const bfraw* __restrict__ proj, const bfraw* __restrict__ WT,
    const void* __restrict__ b_o, void* __restrict__ Cout,
    const void* __restrict__ query, int M)
{
  __shared__ bfraw As[128][40];
  __shared__ bfraw Bs[128][40];
  const int f32m = vote_f32(query);
  const int bm = blockIdx.x * 128;
  const int bn = blockIdx.y * 128;
  const int tid = threadIdx.x;
  const int wave = tid >> 6, lane = tid & 63;
  const int quad = lane >> 4, l16 = lane & 15;
  const int mb = (wave >> 1) * 64, nb = (wave & 1) * 64;
  const int srow = tid >> 1;
  const int sk = (tid & 1) * 16;

  int lr = bm + srow; if (lr >= M) lr = M - 1;
  const size_t aoff = (size_t)lr * 768;

  f32x4 acc[4][4] = {{{0.f}}};

  for (int k0 = 0; k0 < 256; k0 += 32) {
    const bfraw* Ab = proj + aoff + (k0 + sk);
    const uint4 pa0 = ((const uint4*)Ab)[0];
    const uint4 pa1 = ((const uint4*)Ab)[1];
    const bfraw* Bb = WT + (size_t)(1024 + bn + srow) * 256 + (k0 + sk);
    const uint4 pb0 = ((const uint4*)Bb)[0];
    const uint4 pb1 = ((const uint4*)Bb)[1];
    *(uint4*)&As[srow][sk]     = pa0;
    *(uint4*)&As[srow][sk + 8] = pa1;
    *(uint4*)&Bs[srow][sk]     = pb0;
    *(uint4*)&Bs[srow][sk + 8] = pb1;
    __syncthreads();

    bf16x8 af[4], bf[4];
#pragma unroll
    for (int i = 0; i < 4; ++i)
      af[i] = *(const bf16x8*)&As[mb + i * 16 + l16][quad * 8];
#pragma unroll
    for (int j = 0; j < 4; ++j)
      bf[j] = *(const bf16x8*)&Bs[nb + j * 16 + l16][quad * 8];
#pragma unroll
    for (int i = 0; i < 4; ++i)
#pragma unroll
      for (int j = 0; j < 4; ++j)
        acc[i][j] = __builtin_amdgcn_mfma_f32_16x16x32_bf16(af[i], bf[j], acc[i][j], 0, 0, 0);
    __syncthreads();
  }

#pragma unroll
  for (int j = 0; j < 4; ++j) {
    const int col = bn + nb + j * 16 + l16;
    const float bb = loadx(b_o, col, f32m);
#pragma unroll
    for (int i = 0; i < 4; ++i) {
#pragma unroll
      for (int r = 0; r < 4; ++r) {
        const int lrow = bm + mb + i * 16 + quad * 4 + r;
        if (lrow < M) {
          const float v = acc[i][j][r] + bb;
          if (f32m) ((float*)Cout)[(size_t)lrow * 256 + col] = v;
          else      ((bfraw*)Cout)[(size_t)lrow * 256 + col] = f2bf(v);
        }
      }
    }
  }
}

// Sampler, head-major: grid (2040, 8); block = 8 queries x head blockIdx.y.
// x-major dispatch sweeps heads -> live value working set ~1MB (head slice).
// proj row (768 bf16): [0,256) cso | [256,512) tso | [512,640) caw |
// [640,768) taw. Writes core slice (bf16, 32ch) over prow[h*32 .. h*32+32)
// — only this block touches that (query,head) region.
__global__ __launch_bounds__(256, 4) void sampler_k(
    bfraw* __restrict__ proj, const bfraw* __restrict__ value,
    const void* __restrict__ refp, const void* __restrict__ toff,
    const void* __restrict__ query)
{
  __shared__ int   s_idx[256][4];  // clamped pixel index (always valid)
  __shared__ float s_w[256][4];    // attn*bilinear, 0 if OOB

  const int f32m = vote_f32(query);
  const int h = blockIdx.y;
  const int tid = threadIdx.x;
  const int qi = tid >> 5;         // query-in-block 0..7
  const int sp = tid & 31;         // point-in-head
  const int l = sp >> 3;           // level
  const int p = sp & 7;            // 0..3 current, 4..7 temporal
  const int qg = blockIdx.x * 8 + qi;

  const int W_i[4]  = {64, 32, 16, 8};
  const int TH_i[4] = {192, 96, 48, 24};
  const int ST_i[4] = {0, 12288, 15360, 16128};
  const float Wf  = (float)W_i[l];
  const float THf = (float)TH_i[l];

  bfraw* prow = proj + (size_t)qg * 768;

  // ---- joint softmax over 32 logits of (qg, h) — shfl in 32-lane group ----
  const float logit = (p < 4) ? bf2f(prow[512 + h * 16 + l * 4 + p])
                              : bf2f(prow[640 + h * 16 + l * 4 + (p - 4)]);
  float mx = logit;
#pragma unroll
  for (int m = 16; m >= 1; m >>= 1) mx = fmaxf(mx, __shfl_xor(mx, m));
  const float e = __expf(logit - mx);
  float ssum = e;
#pragma unroll
  for (int m = 16; m >= 1; m >>= 1) ssum += __shfl_xor(ssum, m);
  const float attn = e / ssum;

  // ---- sampling location + bilinear corner descriptors ----
  const float rx = loadx(refp, (size_t)(qg * 4 + l) * 2 + 0, f32m);
  const float ry = loadx(refp, (size_t)(qg * 4 + l) * 2 + 1, f32m);
  float ox, oy;
  if (p < 4) {
    ox = bf2f(prow[h * 32 + l * 8 + p * 2 + 0]) / Wf;
    oy = bf2f(prow[h * 32 + l * 8 + p * 2 + 1]) / THf;
  } else {
    const int pj = p - 4, tw = pj >> 1, j = pj & 1;
    ox = loadx(toff, (size_t)(qg * 4 + l) * 4 + tw * 2 + 0, f32m) +
         bf2f(prow[256 + h * 32 + l * 8 + tw * 4 + j * 2 + 0]) / Wf;
    oy = loadx(toff, (size_t)(qg * 4 + l) * 4 + tw * 2 + 1, f32m) +
         bf2f(prow[256 + h * 32 + l * 8 + tw * 4 + j * 2 + 1]) / THf;
  }
  const float x = (rx + ox) * Wf - 0.5f;   // grid_sample align_corners=False
  const float y = (ry + oy) * THf - 0.5f;
  const float x0f = floorf(x), y0f = floorf(y);
  const float lx = x - x0f, ly = y - y0f;
  const int x0 = (int)x0f, y0 = (int)y0f;
  const int Wg = W_i[l], THg = TH_i[l], ST = ST_i[l];
  const float cwx[2] = {1.f - lx, lx};
  const float cwy[2] = {1.f - ly, ly};
#pragma unroll
  for (int c = 0; c < 4; ++c) {
    const int xi = x0 + (c & 1), yi = y0 + (c >> 1);
    const bool inb = (xi >= 0) & (xi < Wg) & (yi >= 0) & (yi < THg);
    const int xc = min(max(xi, 0), Wg - 1);
    const int yc = min(max(yi, 0), THg - 1);
    s_idx[tid][c] = ST + yc * Wg + xc;
    s_w[tid][c] = inb ? (attn * cwx[c & 1] * cwy[c >> 1]) : 0.f;
  }
  __syncthreads();

  // ---- gather: thread = (qi, pt-group pg 0..7, ch-quad chq 0..3) ----
  {
    const int pg = sp >> 2;
    const int chq = sp & 3;
    const bfraw* vb = value + h * 32 + chq * 8;
    int   idx[16];
    float ww[16];
#pragma unroll
    for (int pt = 0; pt < 4; ++pt) {
      const int ds = qi * 32 + pg * 4 + pt;
#pragma unroll
      for (int c = 0; c < 4; ++c) { idx[pt * 4 + c] = s_idx[ds][c]; ww[pt * 4 + c] = s_w[ds][c]; }
    }
    uint4 vv[16];
#pragma unroll
    for (int i = 0; i < 16; ++i) vv[i] = *(const uint4*)(vb + (size_t)idx[i] * 256);
    float acc[8] = {};
#pragma unroll
    for (int i = 0; i < 16; ++i) {
      const float w = ww[i]; const uint4 v = vv[i];
      acc[0] += w * lo16f(v.x); acc[1] += w * hi16f(v.x);
      acc[2] += w * lo16f(v.y); acc[3] += w * hi16f(v.y);
      acc[4] += w * lo16f(v.z); acc[5] += w * hi16f(v.z);
      acc[6] += w * lo16f(v.w); acc[7] += w * hi16f(v.w);
    }
    // reduce over pg (lane bits 2..4 — stays within the 32-lane group)
#pragma unroll
    for (int m = 4; m <= 16; m <<= 1)
#pragma unroll
      for (int r = 0; r < 8; ++r)
        acc[r] += __shfl_xor(acc[r], m);
    if (pg == 0) {   // core overlay: prow[h*32 + chq*8 .. +8) := slice (bf16)
      uint4 pk;
      pk.x = pk2(acc[0], acc[1]);
      pk.y = pk2(acc[2], acc[3]);
      pk.z = pk2(acc[4], acc[5]);
      pk.w = pk2(acc[6], acc[7]);
      *(uint4*)(prow + h * 32 + chq * 8) = pk;
    }
  }
}

extern "C" void kernel_launch(void* const* d_in, const int* in_sizes, int n_in,
                              void* d_out, int out_size, void* d_ws, size_t ws_size,
                              hipStream_t stream)
{
  const void* query  = d_in[0];
  const void* refp   = d_in[1];
  const void* toff   = d_in[2];
  const void* inflat = d_in[3];
  const void* W_so  = d_in[6];
  const void* b_so  = d_in[7];
  const void* W_tso = d_in[8];
  const void* b_tso = d_in[9];
  const void* W_aw  = d_in[10];
  const void* b_aw  = d_in[11];
  const void* W_taw = d_in[12];
  const void* b_taw = d_in[13];
  const void* W_v   = d_in[14];
  const void* b_v   = d_in[15];
  const void* W_o   = d_in[16];
  const void* b_o   = d_in[17];

  const int Lq = 16320;
  // ws: WT bf16 [1280][256] | bcat f32[768] | value bf16 [Lq][256] |
  //     proj bf16 [Lq][768]  (total ~34.1 MB — same footprint R9 ran with)
  const size_t WT_B   = (size_t)1280 * 256 * 2;
  const size_t BCAT_B = 768 * 4;
  const size_t VAL_B  = (size_t)Lq * 256 * 2;
  bfraw* WT    = (bfraw*)d_ws;
  float* bcat  = (float*)((char*)d_ws + WT_B);
  bfraw* value = (bfraw*)((char*)d_ws + WT_B + BCAT_B);
  bfraw* proj  = (bfraw*)((char*)d_ws + WT_B + BCAT_B + VAL_B);

  const dim3 blk(256);
  transpose_k<<<dim3(1283), blk, 0, stream>>>(W_v, W_so, W_tso, W_aw, W_taw, W_o,
                                              b_so, b_tso, b_aw, b_taw, WT, bcat, query);
  gemmVP_k<<<dim3(128, 8), blk, 0, stream>>>(inflat, query, WT, b_v, bcat, value, proj, Lq);
  sampler_k<<<dim3(Lq / 8, 8), blk, 0, stream>>>(proj, value, refp, toff, query);
  gemmO_k<<<dim3(128, 2), blk, 0, stream>>>(proj, WT, b_o, d_out, query, Lq);
}